// Round 17
// baseline (43.802 us; speedup 1.0000x reference)
//
#include <hip/hip_runtime.h>
#include <hip/hip_bf16.h>

// ---------------------------------------------------------------------------
// PGAConjugateLinear as bf16 MFMA GEMM + bias.
// R17: R13 structure, tile 64x96 -> LDS 40KB -> EXACTLY 4 blocks/CU
// (16 waves/CU, +33% TLP vs R13's 12). Grid 64x16 = 1024 = 4/CU balanced.
//   out[b, n=o*3+p] = sum_{k=i*3+r} A[b][k] * Bw[n][k]  +  bias[n]
// GEMM: M=4096, N=1536, K=1536. BK=64, 4 waves (2x2) of 32x48 (acc[2][3]).
// XCD-chunked bijective swizzle (1024%8==0), both-sides XOR LDS swizzle,
// stage-early + __syncthreads double buffer, fused prep.
// Closed paths (measured failures): counted-vmcnt (R6/R7), k-split (R8),
// low-TLP (R9), 8-phase port (R10), reg-staged A (R11), no-XCD-swz (R15),
// cooperative fusion (R14). Gemm structure ceiling ~690 TF; this round
// probes the occupancy axis (the last untried in-structure cell).
// ---------------------------------------------------------------------------

#define B_DIM 4096
#define I_DIM 512
#define O_DIM 512
#define N_DIM (O_DIM * 3)   // 1536
#define K_DIM (I_DIM * 3)   // 1536
#define NT (K_DIM / 64)     // 24 K-steps

typedef __attribute__((ext_vector_type(8))) short bf16x8;
typedef __attribute__((ext_vector_type(4))) float f32x4;

__device__ __forceinline__ unsigned short f2bf(float f) {
    unsigned u = __float_as_uint(f);
    unsigned r = (u + 0x7fffu + ((u >> 16) & 1u)) >> 16;  // RNE
    return (unsigned short)r;
}

__device__ __forceinline__ void gload_lds16(const void* g, void* l) {
    __builtin_amdgcn_global_load_lds(
        (const __attribute__((address_space(1))) unsigned*)g,
        (__attribute__((address_space(3))) unsigned*)l, 16, 0, 0);
}

// Cayley table for Cl(3,0,1), metric [0,1,1,1], reference blade order.
struct Cayley {
    float M[16][16][16];
    float rev[16];
    constexpr Cayley() : M{}, rev{} {
        const unsigned masks[16] = {0u, 1u, 2u, 4u, 8u, 3u, 5u, 9u, 6u, 10u,
                                    12u, 7u, 11u, 13u, 14u, 15u};
        int idx_of[16] = {};
        for (int i = 0; i < 16; ++i) idx_of[masks[i]] = i;
        const int metric[4] = {0, 1, 1, 1};
        for (int i = 0; i < 16; ++i) {
            unsigned a = masks[i];
            for (int j = 0; j < 16; ++j) {
                unsigned b = masks[j];
                int swaps = 0;
                for (int jb = 0; jb < 4; ++jb)
                    if ((b >> jb) & 1u)
                        for (int ia = jb + 1; ia < 4; ++ia)
                            if ((a >> ia) & 1u) ++swaps;
                int sign = (swaps & 1) ? -1 : 1;
                unsigned common = a & b;
                for (int g = 0; g < 4; ++g)
                    if ((common >> g) & 1u) sign *= metric[g];
                if (sign != 0) M[i][j][idx_of[a ^ b]] += (float)sign;
            }
            int grade = 0;
            for (int g = 0; g < 4; ++g) grade += (int)((a >> g) & 1u);
            rev[i] = ((grade * (grade - 1) / 2) % 2) ? -1.f : 1.f;
        }
    }
};
constexpr Cayley CAY{};

// ---------------------------------------------------------------------------
// prep: fused pack_x (blocks 0..1535) + build_w/bias (blocks 1536..2047).
// ---------------------------------------------------------------------------
__global__ __launch_bounds__(512) void prep(const float* __restrict__ x,
                                            const float* __restrict__ weight,
                                            const float* __restrict__ action,
                                            const float* __restrict__ e0,
                                            unsigned short* __restrict__ A,
                                            unsigned short* __restrict__ Bw,
                                            float* __restrict__ bias) {
    const int bid = blockIdx.x;
    const int tid = threadIdx.x;

    if (bid < 1536) {
        // ---- pack: A = bf16(x), flat cast (k=i*3+r is exactly x's layout)
        const size_t t = (size_t)bid * 512 + tid;
        const float4* xp = (const float4*)(x + t * 8);
        const float4 v0 = xp[0], v1 = xp[1];
        const float xs[8] = {v0.x, v0.y, v0.z, v0.w, v1.x, v1.y, v1.z, v1.w};
        unsigned short ov[8];
#pragma unroll
        for (int q = 0; q < 8; ++q) ov[q] = f2bf(xs[q]);
        *(uint4*)(A + t * 8) = *(const uint4*)ov;   // 16B store
        return;
    }

    // ---- build: one block per o, one thread per i.
    const int o = bid - 1536;
    const int i = tid;
    const int t = o * I_DIM + i;
    const int wave = tid >> 6, lane = tid & 63;
    __shared__ float red[8][3];

    constexpr int AB[8] = {0, 5, 6, 7, 8, 9, 10, 15};
    constexpr int PB[3] = {11, 12, 13};
    constexpr int RB[4] = {11, 12, 13, 14};

    float a[8];
    const float* ap = action + (size_t)t * 8;
#pragma unroll
    for (int j = 0; j < 8; ++j) a[j] = ap[j];

    float kv[16], kr[16];
#pragma unroll
    for (int j = 0; j < 16; ++j) { kv[j] = 0.f; kr[j] = 0.f; }
#pragma unroll
    for (int j = 0; j < 8; ++j) {
        kv[AB[j]] = a[j];
        kr[AB[j]] = a[j] * CAY.rev[AB[j]];
    }

    float Am[3][16];
#pragma unroll
    for (int pp = 0; pp < 3; ++pp)
#pragma unroll
        for (int q = 0; q < 16; ++q) {
            float s = 0.f;
#pragma unroll
            for (int tt = 0; tt < 16; ++tt) s += CAY.M[q][PB[pp]][tt] * kr[tt];
            Am[pp][q] = s;
        }

    float Bm[16][4];
#pragma unroll
    for (int q = 0; q < 16; ++q)
#pragma unroll
        for (int rr = 0; rr < 4; ++rr) {
            float s = 0.f;
#pragma unroll
            for (int m = 0; m < 16; ++m) s += CAY.M[m][q][RB[rr]] * kv[m];
            Bm[q][rr] = s;
        }

    const float w = weight[t];
    const float e0i = e0[i];
    float sb[3];
#pragma unroll
    for (int pp = 0; pp < 3; ++pp) {
        float r0 = 0.f, r1 = 0.f, r2 = 0.f, r3 = 0.f;
#pragma unroll
        for (int q = 0; q < 16; ++q) {
            r0 += Am[pp][q] * Bm[q][0];
            r1 += Am[pp][q] * Bm[q][1];
            r2 += Am[pp][q] * Bm[q][2];
            r3 += Am[pp][q] * Bm[q][3];
        }
        unsigned short* bp = Bw + (size_t)(o * 3 + pp) * K_DIM + i * 3;
        bp[0] = f2bf(w * r0);
        bp[1] = f2bf(w * r1);
        bp[2] = f2bf(w * r2);
        sb[pp] = w * r3 * e0i;
    }

#pragma unroll
    for (int off = 32; off; off >>= 1) {
#pragma unroll
        for (int pp = 0; pp < 3; ++pp) sb[pp] += __shfl_down(sb[pp], off, 64);
    }
    if (lane == 0) {
#pragma unroll
        for (int pp = 0; pp < 3; ++pp) red[wave][pp] = sb[pp];
    }
    __syncthreads();
    if (tid == 0) {
#pragma unroll
        for (int pp = 0; pp < 3; ++pp) {
            float s = 0.f;
#pragma unroll
            for (int wv = 0; wv < 8; ++wv) s += red[wv][pp];
            bias[o * 3 + pp] = s;
        }
    }
}

// ---------------------------------------------------------------------------
// gemm: C[m][n] = sum_k A[m][k]*Bw[n][k] + bias[n].
// 256 threads, 4 waves (2x2), wave tile 32x48 (acc[2][3]). Tile 64x96.
// ---------------------------------------------------------------------------
__global__ __launch_bounds__(256, 4) void gemm_bf16(
        const unsigned short* __restrict__ A,
        const unsigned short* __restrict__ Bw,
        const float* __restrict__ bias,
        float* __restrict__ C) {
    __shared__ unsigned short As0[64 * 64], As1[64 * 64];    //  8 KB each
    __shared__ unsigned short Bs0[96 * 64], Bs1[96 * 64];    // 12 KB each
    // 40 KB total -> 4 blocks/CU (16 waves/CU).

    const int tid = threadIdx.x;
    const int wave = tid >> 6, lane = tid & 63;

    // XCD-chunked bijective swizzle (1024 % 8 == 0), m-tile-major in chunk.
    const int bid = blockIdx.x;
    const int swz = (bid & 7) * 128 + (bid >> 3);
    const int mt = swz >> 4, nt = swz & 15;
    const int m0 = mt * 64, n0 = nt * 96;
    const int wr = wave >> 1, wc = wave & 1;     // 2x2 wave grid, 32x48 each

    // staging: 16B segs; seg s -> LDS byte s*16 (linear); global col-seg
    // = (s&7)^(row&7)  [both-sides XOR swizzle]; row=(s>>6)*8+(s&7) via the
    // R13 slot formula generalized. A: 512 segs (2/thread), B: 768 segs
    // (3/thread); 5 loads/thread, uniform.
    const unsigned short* aSrc[2];
    int aOff[2];
#pragma unroll
    for (int q = 0; q < 2; ++q) {
        const int s = tid + q * 256;
        aSrc[q] = A + (size_t)(m0 + (s >> 3)) * K_DIM +
                  (((s & 7) ^ ((s >> 3) & 7)) * 8);
        aOff[q] = s * 8;
    }
    const unsigned short* bSrc[3];
    int bOff[3];
#pragma unroll
    for (int q = 0; q < 3; ++q) {
        const int s = tid + q * 256;
        bSrc[q] = Bw + (size_t)(n0 + (s >> 3)) * K_DIM +
                  (((s & 7) ^ ((s >> 3) & 7)) * 8);
        bOff[q] = s * 8;
    }

    // fragment read: row r, global col-seg g -> elem r*64 + ((g)^(r&7))*8
    const int frow = lane & 15;
    const int g0 = lane >> 4;

    f32x4 acc[2][3] = {};

#define STAGE(AS, BS, K0)                                    \
    do {                                                     \
        gload_lds16(aSrc[0] + (K0), (AS) + aOff[0]);         \
        gload_lds16(aSrc[1] + (K0), (AS) + aOff[1]);         \
        _Pragma("unroll")                                    \
        for (int q = 0; q < 3; ++q)                          \
            gload_lds16(bSrc[q] + (K0), (BS) + bOff[q]);     \
    } while (0)

#define COMPUTE(AS, BS)                                                        \
    do {                                                                       \
        bf16x8 af[2][2], bfr[2][3];                                            \
        _Pragma("unroll")                                                      \
        for (int kh = 0; kh < 2; ++kh) {                                       \
            _Pragma("unroll")                                                  \
            for (int mi = 0; mi < 2; ++mi) {                                   \
                const int r = wr * 32 + mi * 16 + frow;                        \
                af[kh][mi] =                                                   \
                    *(const bf16x8*)&(AS)[r * 64 + ((g0 + kh * 4) ^ (r & 7)) * 8]; \
            }                                                                  \
            _Pragma("unroll")                                                  \
            for (int ni = 0; ni < 3; ++ni) {                                   \
                const int r = wc * 48 + ni * 16 + frow;                        \
                bfr[kh][ni] =                                                  \
                    *(const bf16x8*)&(BS)[r * 64 + ((g0 + kh * 4) ^ (r & 7)) * 8]; \
            }                                                                  \
        }                                                                      \
        _Pragma("unroll")                                                      \
        for (int kh = 0; kh < 2; ++kh)                                         \
            _Pragma("unroll")                                                  \
            for (int mi = 0; mi < 2; ++mi)                                     \
                _Pragma("unroll")                                              \
                for (int ni = 0; ni < 3; ++ni)                                 \
                    acc[mi][ni] = __builtin_amdgcn_mfma_f32_16x16x32_bf16(     \
                        af[kh][mi], bfr[kh][ni], acc[mi][ni], 0, 0, 0);        \
    } while (0)

    STAGE(As0, Bs0, 0);
    __syncthreads();                       // buf0 ready

#pragma unroll 1
    for (int t = 0; t < NT - 2; t += 2) {
        STAGE(As1, Bs1, (t + 1) * 64);     // issue next-tile loads FIRST
        COMPUTE(As0, Bs0);                 // MFMA + other waves hide latency
        __syncthreads();
        STAGE(As0, Bs0, (t + 2) * 64);
        COMPUTE(As1, Bs1);
        __syncthreads();
    }
    STAGE(As1, Bs1, (NT - 1) * 64);
    COMPUTE(As0, Bs0);
    __syncthreads();
    COMPUTE(As1, Bs1);

#undef STAGE
#undef COMPUTE

    // epilogue: C/D layout col = lane&15, row = (lane>>4)*4 + j; add bias[n]
    const int crow = (lane >> 4) * 4;
    const int ccol = lane & 15;
#pragma unroll
    for (int mi = 0; mi < 2; ++mi)
#pragma unroll
        for (int ni = 0; ni < 3; ++ni) {
            const int n = n0 + wc * 48 + ni * 16 + ccol;
            const float bv = bias[n];
            float* cp = C + (size_t)(m0 + wr * 32 + mi * 16 + crow) * N_DIM + n;
#pragma unroll
            for (int j = 0; j < 4; ++j) cp[(size_t)j * N_DIM] = acc[mi][ni][j] + bv;
        }
}

// ---------------------------------------------------------------------------
extern "C" void kernel_launch(void* const* d_in, const int* in_sizes, int n_in,
                              void* d_out, int out_size, void* d_ws, size_t ws_size,
                              hipStream_t stream) {
    const float* x      = (const float*)d_in[0];  // (4096, 512, 3)
    const float* weight = (const float*)d_in[1];  // (512, 512)
    const float* action = (const float*)d_in[2];  // (512, 512, 8)
    const float* e0     = (const float*)d_in[3];  // (512, 1)
    float* out = (float*)d_out;                   // (4096, 512, 3)

    unsigned short* Bw = (unsigned short*)d_ws;                 // 4.7 MB
    unsigned short* Ap = Bw + (size_t)N_DIM * K_DIM;            // 12.6 MB
    float* bias = (float*)(Ap + (size_t)B_DIM * K_DIM);         // 1536 f32

    hipLaunchKernelGGL(prep, dim3(2048), dim3(512), 0, stream,
                       x, weight, action, e0, Ap, Bw, bias);
    hipLaunchKernelGGL(gemm_bf16, dim3(1024), dim3(256), 0, stream,
                       Ap, Bw, bias, out);
}

// Round 18
// 42.756 us; speedup vs baseline: 1.0245x; 1.0245x over previous
//
#include <hip/hip_runtime.h>
#include <hip/hip_bf16.h>

// ---------------------------------------------------------------------------
// PGAConjugateLinear as bf16 MFMA GEMM + bias.  FINAL (R13/R16 configuration,
// best measured: 42.4-42.9 us; R17's 4-block/CU probe was null -> occupancy
// axis convergence-confirmed at 12 waves/CU).
//   out[b, n=o*3+p] = sum_{k=i*3+r} A[b][k] * Bw[n][k]  +  bias[n]
//   A[b][k]  = bf16(x[b][k])   (x is (4096,512,3) contiguous -> flat cast)
//   Bw[n][k] = weight[o,i] * T_oi[p][r]   (bf16, B^T layout, r in 0..2)
//   bias[n]  = sum_i weight[o,i] * T_oi[p][3] * e0[i]  (e123 column folded)
// GEMM: M=4096, N=1536, K=1536. Tile 64x128, BK=64, 4 waves (2x2) of 32x64,
// grid 768 = exactly 3 blocks/CU (12 waves/CU), XCD-chunked bijective block
// swizzle (R15: removing costs ~2us), both-sides XOR LDS swizzle (0 bank
// conflicts), stage-early + __syncthreads double buffer, fused prep.
// Ceiling: gemm ~28us ~690 TF = plain-HIP 2-phase structure ceiling
// (m230/m233); prep ~ HBM floor. Closed paths (measured): counted-vmcnt
// (R6/R7), k-split (R8 spill), low-TLP (R9), 8-phase port (R10, geometry-
// blocked at N=1536), reg-staged A (R11), coop fusion (R14), no-swz (R15),
// 4 blocks/CU (R17).
// ---------------------------------------------------------------------------

#define B_DIM 4096
#define I_DIM 512
#define O_DIM 512
#define N_DIM (O_DIM * 3)   // 1536
#define K_DIM (I_DIM * 3)   // 1536
#define NT (K_DIM / 64)     // 24 K-steps

typedef __attribute__((ext_vector_type(8))) short bf16x8;
typedef __attribute__((ext_vector_type(4))) float f32x4;

__device__ __forceinline__ unsigned short f2bf(float f) {
    unsigned u = __float_as_uint(f);
    unsigned r = (u + 0x7fffu + ((u >> 16) & 1u)) >> 16;  // RNE
    return (unsigned short)r;
}

__device__ __forceinline__ void gload_lds16(const void* g, void* l) {
    __builtin_amdgcn_global_load_lds(
        (const __attribute__((address_space(1))) unsigned*)g,
        (__attribute__((address_space(3))) unsigned*)l, 16, 0, 0);
}

// Cayley table for Cl(3,0,1), metric [0,1,1,1], reference blade order.
struct Cayley {
    float M[16][16][16];
    float rev[16];
    constexpr Cayley() : M{}, rev{} {
        const unsigned masks[16] = {0u, 1u, 2u, 4u, 8u, 3u, 5u, 9u, 6u, 10u,
                                    12u, 7u, 11u, 13u, 14u, 15u};
        int idx_of[16] = {};
        for (int i = 0; i < 16; ++i) idx_of[masks[i]] = i;
        const int metric[4] = {0, 1, 1, 1};
        for (int i = 0; i < 16; ++i) {
            unsigned a = masks[i];
            for (int j = 0; j < 16; ++j) {
                unsigned b = masks[j];
                int swaps = 0;
                for (int jb = 0; jb < 4; ++jb)
                    if ((b >> jb) & 1u)
                        for (int ia = jb + 1; ia < 4; ++ia)
                            if ((a >> ia) & 1u) ++swaps;
                int sign = (swaps & 1) ? -1 : 1;
                unsigned common = a & b;
                for (int g = 0; g < 4; ++g)
                    if ((common >> g) & 1u) sign *= metric[g];
                if (sign != 0) M[i][j][idx_of[a ^ b]] += (float)sign;
            }
            int grade = 0;
            for (int g = 0; g < 4; ++g) grade += (int)((a >> g) & 1u);
            rev[i] = ((grade * (grade - 1) / 2) % 2) ? -1.f : 1.f;
        }
    }
};
constexpr Cayley CAY{};

// ---------------------------------------------------------------------------
// prep: fused pack_x (blocks 0..1535) + build_w/bias (blocks 1536..2047).
// BW-bound pack blocks and VALU-bound build blocks co-schedule on CUs.
// ---------------------------------------------------------------------------
__global__ __launch_bounds__(512) void prep(const float* __restrict__ x,
                                            const float* __restrict__ weight,
                                            const float* __restrict__ action,
                                            const float* __restrict__ e0,
                                            unsigned short* __restrict__ A,
                                            unsigned short* __restrict__ Bw,
                                            float* __restrict__ bias) {
    const int bid = blockIdx.x;
    const int tid = threadIdx.x;

    if (bid < 1536) {
        // ---- pack: A = bf16(x), flat cast (k=i*3+r is exactly x's layout)
        const size_t t = (size_t)bid * 512 + tid;
        const float4* xp = (const float4*)(x + t * 8);
        const float4 v0 = xp[0], v1 = xp[1];
        const float xs[8] = {v0.x, v0.y, v0.z, v0.w, v1.x, v1.y, v1.z, v1.w};
        unsigned short ov[8];
#pragma unroll
        for (int q = 0; q < 8; ++q) ov[q] = f2bf(xs[q]);
        *(uint4*)(A + t * 8) = *(const uint4*)ov;   // 16B store
        return;
    }

    // ---- build: one block per o, one thread per i.
    const int o = bid - 1536;
    const int i = tid;
    const int t = o * I_DIM + i;
    const int wave = tid >> 6, lane = tid & 63;
    __shared__ float red[8][3];

    constexpr int AB[8] = {0, 5, 6, 7, 8, 9, 10, 15};
    constexpr int PB[3] = {11, 12, 13};
    constexpr int RB[4] = {11, 12, 13, 14};

    float a[8];
    const float* ap = action + (size_t)t * 8;
#pragma unroll
    for (int j = 0; j < 8; ++j) a[j] = ap[j];

    float kv[16], kr[16];
#pragma unroll
    for (int j = 0; j < 16; ++j) { kv[j] = 0.f; kr[j] = 0.f; }
#pragma unroll
    for (int j = 0; j < 8; ++j) {
        kv[AB[j]] = a[j];
        kr[AB[j]] = a[j] * CAY.rev[AB[j]];
    }

    float Am[3][16];
#pragma unroll
    for (int pp = 0; pp < 3; ++pp)
#pragma unroll
        for (int q = 0; q < 16; ++q) {
            float s = 0.f;
#pragma unroll
            for (int tt = 0; tt < 16; ++tt) s += CAY.M[q][PB[pp]][tt] * kr[tt];
            Am[pp][q] = s;
        }

    float Bm[16][4];
#pragma unroll
    for (int q = 0; q < 16; ++q)
#pragma unroll
        for (int rr = 0; rr < 4; ++rr) {
            float s = 0.f;
#pragma unroll
            for (int m = 0; m < 16; ++m) s += CAY.M[m][q][RB[rr]] * kv[m];
            Bm[q][rr] = s;
        }

    const float w = weight[t];
    const float e0i = e0[i];
    float sb[3];
#pragma unroll
    for (int pp = 0; pp < 3; ++pp) {
        float r0 = 0.f, r1 = 0.f, r2 = 0.f, r3 = 0.f;
#pragma unroll
        for (int q = 0; q < 16; ++q) {
            r0 += Am[pp][q] * Bm[q][0];
            r1 += Am[pp][q] * Bm[q][1];
            r2 += Am[pp][q] * Bm[q][2];
            r3 += Am[pp][q] * Bm[q][3];
        }
        unsigned short* bp = Bw + (size_t)(o * 3 + pp) * K_DIM + i * 3;
        bp[0] = f2bf(w * r0);
        bp[1] = f2bf(w * r1);
        bp[2] = f2bf(w * r2);
        sb[pp] = w * r3 * e0i;
    }

#pragma unroll
    for (int off = 32; off; off >>= 1) {
#pragma unroll
        for (int pp = 0; pp < 3; ++pp) sb[pp] += __shfl_down(sb[pp], off, 64);
    }
    if (lane == 0) {
#pragma unroll
        for (int pp = 0; pp < 3; ++pp) red[wave][pp] = sb[pp];
    }
    __syncthreads();
    if (tid == 0) {
#pragma unroll
        for (int pp = 0; pp < 3; ++pp) {
            float s = 0.f;
#pragma unroll
            for (int wv = 0; wv < 8; ++wv) s += red[wv][pp];
            bias[o * 3 + pp] = s;
        }
    }
}

// ---------------------------------------------------------------------------
// gemm: C[m][n] = sum_k A[m][k]*Bw[n][k] + bias[n].
// 256 threads, 4 waves (2x2), wave tile 32x64 (acc[2][4]).
// ---------------------------------------------------------------------------
__global__ __launch_bounds__(256, 3) void gemm_bf16(
        const unsigned short* __restrict__ A,
        const unsigned short* __restrict__ Bw,
        const float* __restrict__ bias,
        float* __restrict__ C) {
    __shared__ unsigned short As0[64 * 64], As1[64 * 64];    //  8 KB each
    __shared__ unsigned short Bs0[128 * 64], Bs1[128 * 64];  // 16 KB each
    // 48 KB total -> 3 blocks/CU (12 waves/CU).

    const int tid = threadIdx.x;
    const int wave = tid >> 6, lane = tid & 63;

    // XCD-chunked bijective swizzle (768 % 8 == 0), m-tile-major in chunk.
    const int bid = blockIdx.x;
    const int swz = (bid & 7) * 96 + (bid >> 3);
    const int mt = swz / 12, nt = swz - mt * 12;
    const int m0 = mt * 64, n0 = nt * 128;
    const int wr = wave >> 1, wc = wave & 1;     // 2x2 wave grid, 32x64 each

    // staging: 16B segs; seg s -> LDS byte s*16 (linear); global col-seg
    // = (s&7)^(row&7)   [both-sides XOR swizzle]. A: 512 segs (2/thread),
    // B: 1024 segs (4/thread); 6 loads/thread, uniform.
    const unsigned short* aSrc[2];
    int aOff[2];
#pragma unroll
    for (int q = 0; q < 2; ++q) {
        const int s = tid + q * 256;
        aSrc[q] = A + (size_t)(m0 + (s >> 3)) * K_DIM +
                  (((s & 7) ^ ((s >> 3) & 7)) * 8);
        aOff[q] = s * 8;
    }
    const unsigned short* bSrc[4];
    int bOff[4];
#pragma unroll
    for (int q = 0; q < 4; ++q) {
        const int s = tid + q * 256;
        bSrc[q] = Bw + (size_t)(n0 + (s >> 3)) * K_DIM +
                  (((s & 7) ^ ((s >> 3) & 7)) * 8);
        bOff[q] = s * 8;
    }

    // fragment read: row r, global col-seg g -> elem r*64 + ((g)^(r&7))*8
    const int frow = lane & 15;
    const int g0 = lane >> 4;

    f32x4 acc[2][4] = {};

#define STAGE(AS, BS, K0)                                    \
    do {                                                     \
        gload_lds16(aSrc[0] + (K0), (AS) + aOff[0]);         \
        gload_lds16(aSrc[1] + (K0), (AS) + aOff[1]);         \
        _Pragma("unroll")                                    \
        for (int q = 0; q < 4; ++q)                          \
            gload_lds16(bSrc[q] + (K0), (BS) + bOff[q]);     \
    } while (0)

#define COMPUTE(AS, BS)                                                        \
    do {                                                                       \
        bf16x8 af[2][2], bfr[2][4];                                            \
        _Pragma("unroll")                                                      \
        for (int kh = 0; kh < 2; ++kh) {                                       \
            _Pragma("unroll")                                                  \
            for (int mi = 0; mi < 2; ++mi) {                                   \
                const int r = wr * 32 + mi * 16 + frow;                        \
                af[kh][mi] =                                                   \
                    *(const bf16x8*)&(AS)[r * 64 + ((g0 + kh * 4) ^ (r & 7)) * 8]; \
            }                                                                  \
            _Pragma("unroll")                                                  \
            for (int ni = 0; ni < 4; ++ni) {                                   \
                const int r = wc * 64 + ni * 16 + frow;                        \
                bfr[kh][ni] =                                                  \
                    *(const bf16x8*)&(BS)[r * 64 + ((g0 + kh * 4) ^ (r & 7)) * 8]; \
            }                                                                  \
        }                                                                      \
        _Pragma("unroll")                                                      \
        for (int kh = 0; kh < 2; ++kh)                                         \
            _Pragma("unroll")                                                  \
            for (int mi = 0; mi < 2; ++mi)                                     \
                _Pragma("unroll")                                              \
                for (int ni = 0; ni < 4; ++ni)                                 \
                    acc[mi][ni] = __builtin_amdgcn_mfma_f32_16x16x32_bf16(     \
                        af[kh][mi], bfr[kh][ni], acc[mi][ni], 0, 0, 0);        \
    } while (0)

    STAGE(As0, Bs0, 0);
    __syncthreads();                       // buf0 ready

#pragma unroll 1
    for (int t = 0; t < NT - 2; t += 2) {
        STAGE(As1, Bs1, (t + 1) * 64);     // issue next-tile loads FIRST
        COMPUTE(As0, Bs0);                 // MFMA + other waves hide latency
        __syncthreads();
        STAGE(As0, Bs0, (t + 2) * 64);
        COMPUTE(As1, Bs1);
        __syncthreads();
    }
    STAGE(As1, Bs1, (NT - 1) * 64);
    COMPUTE(As0, Bs0);
    __syncthreads();
    COMPUTE(As1, Bs1);

#undef STAGE
#undef COMPUTE

    // epilogue: C/D layout col = lane&15, row = (lane>>4)*4 + j; add bias[n]
    const int crow = (lane >> 4) * 4;
    const int ccol = lane & 15;
#pragma unroll
    for (int mi = 0; mi < 2; ++mi)
#pragma unroll
        for (int ni = 0; ni < 4; ++ni) {
            const int n = n0 + wc * 64 + ni * 16 + ccol;
            const float bv = bias[n];
            float* cp = C + (size_t)(m0 + wr * 32 + mi * 16 + crow) * N_DIM + n;
#pragma unroll
            for (int j = 0; j < 4; ++j) cp[(size_t)j * N_DIM] = acc[mi][ni][j] + bv;
        }
}

// ---------------------------------------------------------------------------
extern "C" void kernel_launch(void* const* d_in, const int* in_sizes, int n_in,
                              void* d_out, int out_size, void* d_ws, size_t ws_size,
                              hipStream_t stream) {
    const float* x      = (const float*)d_in[0];  // (4096, 512, 3)
    const float* weight = (const float*)d_in[1];  // (512, 512)
    const float* action = (const float*)d_in[2];  // (512, 512, 8)
    const float* e0     = (const float*)d_in[3];  // (512, 1)
    float* out = (float*)d_out;                   // (4096, 512, 3)

    unsigned short* Bw = (unsigned short*)d_ws;                 // 4.7 MB
    unsigned short* Ap = Bw + (size_t)N_DIM * K_DIM;            // 12.6 MB
    float* bias = (float*)(Ap + (size_t)B_DIM * K_DIM);         // 1536 f32

    hipLaunchKernelGGL(prep, dim3(2048), dim3(512), 0, stream,
                       x, weight, action, e0, Ap, Bw, bias);
    hipLaunchKernelGGL(gemm_bf16, dim3(768), dim3(256), 0, stream,
                       Ap, Bw, bias, out);
}